// Round 8
// baseline (1514.371 us; speedup 1.0000x reference)
//
#include <hip/hip_runtime.h>
#include <hip/hip_fp16.h>
#include <hip/hip_cooperative_groups.h>

namespace cg = cooperative_groups;

#define N_NODES 50000
#define HID 128
#define CLS 64
#define NBINS 196              // ceil(50000/256) node bins
#define MAXG 2048
#define CAST_T (N_NODES * HID / 4)   // 1,600,000 float4 groups of x
#define WTOT 57344                   // 3*128*128 + 64*128 weight elements

typedef __attribute__((ext_vector_type(8))) _Float16 f16x8;
typedef __attribute__((ext_vector_type(4))) float f32x4;

struct MegaParams {
    const float* x;
    const int* row;
    const int* col;
    const float* b0; const float* b1; const float* b2; const float* bl;
    const float* W0; const float* W1; const float* W2; const float* Wl;
    float* out;
    int* hist; int* hlocal; int* binTot; int* nodeTot;
    int* sbuf_src; unsigned char* sbuf_c;
    int* row_ptr; float* dinv; int2* csr_sw;
    __half* h2; __half* hA;
    __half* W0h; __half* W0l; __half* W1h; __half* W1l;
    __half* W2h; __half* W2l; __half* Wlh; __half* Wll;
    int E; int chunk;
};

// ---- shared (coexist; ~7 KB total) ----
// sh_base persists P2->P4 (binBase), sh_lcnt persists P3->P4 (per-node degree).
__shared__ int sh_hist[NBINS];
__shared__ int sh_s[256];
__shared__ int sh_base[NBINS + 1];
__shared__ int sh_nbase[256];
__shared__ int sh_cur[256];
__shared__ int sh_lcnt[256];
__shared__ float sh_dloc[256];

__device__ __forceinline__ int block_scan_excl(int v, int* s, int* totalOut) {
    int t = threadIdx.x;
    s[t] = v;
    __syncthreads();
#pragma unroll
    for (int off = 1; off < 256; off <<= 1) {
        int u = (t >= off) ? s[t - off] : 0;
        __syncthreads();
        s[t] += u;
        __syncthreads();
    }
    int incl = s[t];
    if (totalOut) *totalOut = s[255];
    return incl - v;  // caller must __syncthreads() before reusing s
}

// ---------------- f16 MFMA GEMM phase: C = A @ (Wh+Wl) (+bias) ----------------
template<int NC, bool ADD_BIAS, bool HALF_OUT>
__device__ void gemm_phase(const __half* __restrict__ A, const __half* __restrict__ Bh,
                           const __half* __restrict__ Bl, const float* __restrict__ bias,
                           void* __restrict__ Cv, int G) {
    constexpr int NT = NC / 16;
    int lane = threadIdx.x & 63;
    int wave = threadIdx.x >> 6;
    int mr = lane & 15;
    int kq = (lane >> 4) << 3;  // 0,8,16,24
    const int nStripes = N_NODES / 16;  // 3125 exactly (no tail)
    for (int sId = blockIdx.x * 4 + wave; sId < nStripes; sId += G * 4) {
        int m0 = sId << 4;
        const __half* ap = A + (size_t)(m0 + mr) * 128 + kq;
        const __half* bh = Bh + (size_t)mr * 128 + kq;
        const __half* bl = Bl + (size_t)mr * 128 + kq;
        f32x4 acc[NT];
#pragma unroll
        for (int t = 0; t < NT; ++t) acc[t] = (f32x4){0.f, 0.f, 0.f, 0.f};
#pragma unroll
        for (int kc = 0; kc < 128; kc += 32) {
            f16x8 a = *(const f16x8*)(ap + kc);
#pragma unroll
            for (int t = 0; t < NT; ++t) {
                f16x8 wh = *(const f16x8*)(bh + (size_t)t * 16 * 128 + kc);
                f16x8 wl = *(const f16x8*)(bl + (size_t)t * 16 * 128 + kc);
                acc[t] = __builtin_amdgcn_mfma_f32_16x16x32_f16(a, wh, acc[t], 0, 0, 0);
                acc[t] = __builtin_amdgcn_mfma_f32_16x16x32_f16(a, wl, acc[t], 0, 0, 0);
            }
        }
        // C/D layout: col = lane&15, row = (lane>>4)*4 + reg
        int r0 = m0 + ((lane >> 4) << 2);
        int cc = lane & 15;
#pragma unroll
        for (int t = 0; t < NT; ++t) {
            float bsv = ADD_BIAS ? bias[t * 16 + cc] : 0.f;
#pragma unroll
            for (int r = 0; r < 4; ++r) {
                float val = acc[t][r] + bsv;
                size_t idx = (size_t)(r0 + r) * NC + t * 16 + cc;
                if (HALF_OUT)
                    ((__half*)Cv)[idx] = __float2half_rn(val);
                else
                    ((float*)Cv)[idx] = val;
            }
        }
    }
}

// ---------------- aggregation phase: one wave per node ----------------
__device__ void agg_phase(const __half* __restrict__ h2, const int* __restrict__ row_ptr,
                          const int2* __restrict__ csr_sw, const float* __restrict__ dinv,
                          const float* __restrict__ bias, __half* __restrict__ outA, int G) {
    int lane = threadIdx.x & 63;
    int wave = threadIdx.x >> 6;
    int loff = lane << 1;
    for (int wid = blockIdx.x * 4 + wave; wid < N_NODES; wid += G * 4) {
        int beg = row_ptr[wid];
        int end = row_ptr[wid + 1];
        float dv = dinv[wid];
        float ax = 0.f, ay = 0.f;
        for (int base = beg; base < end; base += 64) {
            int cnt = end - base;
            if (cnt > 64) cnt = 64;
            int msrc = 0;
            float mw = 0.f;
            if (lane < cnt) {
                int2 e = csr_sw[base + lane];
                msrc = e.x;
                mw = __int_as_float(e.y);
            }
            int j = 0;
            for (; j + 8 <= cnt; j += 8) {
                int s0 = __shfl(msrc, j),     s1 = __shfl(msrc, j + 1);
                int s2 = __shfl(msrc, j + 2), s3 = __shfl(msrc, j + 3);
                int s4 = __shfl(msrc, j + 4), s5 = __shfl(msrc, j + 5);
                int s6 = __shfl(msrc, j + 6), s7 = __shfl(msrc, j + 7);
                float w0 = __shfl(mw, j),     w1 = __shfl(mw, j + 1);
                float w2 = __shfl(mw, j + 2), w3 = __shfl(mw, j + 3);
                float w4 = __shfl(mw, j + 4), w5 = __shfl(mw, j + 5);
                float w6 = __shfl(mw, j + 6), w7 = __shfl(mw, j + 7);
                float2 v0 = __half22float2(*(const __half2*)(h2 + ((size_t)s0 << 7) + loff));
                float2 v1 = __half22float2(*(const __half2*)(h2 + ((size_t)s1 << 7) + loff));
                float2 v2 = __half22float2(*(const __half2*)(h2 + ((size_t)s2 << 7) + loff));
                float2 v3 = __half22float2(*(const __half2*)(h2 + ((size_t)s3 << 7) + loff));
                float2 v4 = __half22float2(*(const __half2*)(h2 + ((size_t)s4 << 7) + loff));
                float2 v5 = __half22float2(*(const __half2*)(h2 + ((size_t)s5 << 7) + loff));
                float2 v6 = __half22float2(*(const __half2*)(h2 + ((size_t)s6 << 7) + loff));
                float2 v7 = __half22float2(*(const __half2*)(h2 + ((size_t)s7 << 7) + loff));
                ax = fmaf(v0.x, w0, ax); ay = fmaf(v0.y, w0, ay);
                ax = fmaf(v1.x, w1, ax); ay = fmaf(v1.y, w1, ay);
                ax = fmaf(v2.x, w2, ax); ay = fmaf(v2.y, w2, ay);
                ax = fmaf(v3.x, w3, ax); ay = fmaf(v3.y, w3, ay);
                ax = fmaf(v4.x, w4, ax); ay = fmaf(v4.y, w4, ay);
                ax = fmaf(v5.x, w5, ax); ay = fmaf(v5.y, w5, ay);
                ax = fmaf(v6.x, w6, ax); ay = fmaf(v6.y, w6, ay);
                ax = fmaf(v7.x, w7, ax); ay = fmaf(v7.y, w7, ay);
            }
            for (; j + 4 <= cnt; j += 4) {
                int s0 = __shfl(msrc, j),     s1 = __shfl(msrc, j + 1);
                int s2 = __shfl(msrc, j + 2), s3 = __shfl(msrc, j + 3);
                float w0 = __shfl(mw, j),     w1 = __shfl(mw, j + 1);
                float w2 = __shfl(mw, j + 2), w3 = __shfl(mw, j + 3);
                float2 v0 = __half22float2(*(const __half2*)(h2 + ((size_t)s0 << 7) + loff));
                float2 v1 = __half22float2(*(const __half2*)(h2 + ((size_t)s1 << 7) + loff));
                float2 v2 = __half22float2(*(const __half2*)(h2 + ((size_t)s2 << 7) + loff));
                float2 v3 = __half22float2(*(const __half2*)(h2 + ((size_t)s3 << 7) + loff));
                ax = fmaf(v0.x, w0, ax); ay = fmaf(v0.y, w0, ay);
                ax = fmaf(v1.x, w1, ax); ay = fmaf(v1.y, w1, ay);
                ax = fmaf(v2.x, w2, ax); ay = fmaf(v2.y, w2, ay);
                ax = fmaf(v3.x, w3, ax); ay = fmaf(v3.y, w3, ay);
            }
            for (; j < cnt; ++j) {
                int s = __shfl(msrc, j);
                float w = __shfl(mw, j);
                float2 v = __half22float2(*(const __half2*)(h2 + ((size_t)s << 7) + loff));
                ax = fmaf(v.x, w, ax); ay = fmaf(v.y, w, ay);
            }
        }
        float sn = dv * dv;
        float2 self = __half22float2(*(const __half2*)(h2 + ((size_t)wid << 7) + loff));
        float2 b = *(const float2*)(bias + loff);
        float ox = fmaxf(fmaf(self.x, sn, ax) + b.x, 0.f);
        float oy = fmaxf(fmaf(self.y, sn, ay) + b.y, 0.f);
        *(__half2*)(outA + ((size_t)wid << 7) + loff) = __float22half2_rn(make_float2(ox, oy));
    }
}

// ---------------- the mega kernel: all 12 phases, 11 grid syncs ----------------
__global__ __launch_bounds__(256, 6) void mega_kernel(MegaParams p) {
    cg::grid_group grid = cg::this_grid();
    const int G = gridDim.x;
    const int bid = blockIdx.x;
    const int tid = threadIdx.x;

    // ---- P0: x cast + W transpose/split, plus per-(block,bin) histogram ----
    for (int idx = bid * 256 + tid; idx < CAST_T + WTOT; idx += G * 256) {
        if (idx < CAST_T) {
            float4 v = ((const float4*)p.x)[idx];
            ((__half2*)p.hA)[idx * 2] = __float22half2_rn(make_float2(v.x, v.y));
            ((__half2*)p.hA)[idx * 2 + 1] = __float22half2_rn(make_float2(v.z, v.w));
            continue;
        }
        int widx = idx - CAST_T;
        const float* W;
        __half *oh, *ol;
        int NCdim, local;
        if (widx < 16384)      { W = p.W0; oh = p.W0h; ol = p.W0l; NCdim = 128; local = widx; }
        else if (widx < 32768) { W = p.W1; oh = p.W1h; ol = p.W1l; NCdim = 128; local = widx - 16384; }
        else if (widx < 49152) { W = p.W2; oh = p.W2h; ol = p.W2l; NCdim = 128; local = widx - 32768; }
        else                   { W = p.Wl; oh = p.Wlh; ol = p.Wll; NCdim = 64;  local = widx - 49152; }
        int nn = local >> 7;
        int k = local & 127;
        float v = W[(size_t)k * NCdim + nn];
        __half h = __float2half_rn(v);
        oh[local] = h;
        ol[local] = __float2half_rn(v - __half2float(h));
    }
    for (int i = tid; i < NBINS; i += 256) sh_hist[i] = 0;
    __syncthreads();
    {
        int beg = bid * p.chunk, end = min(p.E, beg + p.chunk);
        if (beg < end) {
            int vend = beg + ((end - beg) & ~3);
            for (int i = beg + tid * 4; i < vend; i += 1024) {
                int4 c4 = *(const int4*)(p.col + i);
                atomicAdd(&sh_hist[c4.x >> 8], 1);
                atomicAdd(&sh_hist[c4.y >> 8], 1);
                atomicAdd(&sh_hist[c4.z >> 8], 1);
                atomicAdd(&sh_hist[c4.w >> 8], 1);
            }
            int i = vend + tid;
            if (i < end) atomicAdd(&sh_hist[p.col[i] >> 8], 1);
        }
    }
    __syncthreads();
    for (int i = tid; i < NBINS; i += 256) p.hist[(size_t)i * G + bid] = sh_hist[i];
    grid.sync();

    // ---- P1: per-bin exclusive scan of its G block-counts ----
    if (bid < NBINS) {
        int run = 0;
        for (int base = 0; base < G; base += 256) {
            int j = base + tid;
            int v = (j < G) ? p.hist[(size_t)bid * G + j] : 0;
            int tot;
            int excl = block_scan_excl(v, sh_s, &tot);
            if (j < G) p.hlocal[(size_t)bid * G + j] = run + excl;
            __syncthreads();
            run += tot;
        }
        if (tid == 0) p.binTot[bid] = run;
    }
    grid.sync();

    // ---- P2: scatter edges bin-sorted (binBase computed per-block in LDS) ----
    {
        int v = (tid < NBINS) ? p.binTot[tid] : 0;
        int tot;
        int excl = block_scan_excl(v, sh_s, &tot);
        if (tid < NBINS) sh_base[tid] = excl;
        if (tid == 0) sh_base[NBINS] = tot;  // == E
        __syncthreads();
        for (int i = tid; i < NBINS; i += 256)
            sh_cur[i] = sh_base[i] + p.hlocal[(size_t)i * G + bid];
        __syncthreads();
        int beg = bid * p.chunk, end = min(p.E, beg + p.chunk);
        if (beg < end) {
            int vend = beg + ((end - beg) & ~3);
            for (int i = beg + tid * 4; i < vend; i += 1024) {
                int4 c4 = *(const int4*)(p.col + i);
                int4 r4 = *(const int4*)(p.row + i);
                int pp;
                pp = atomicAdd(&sh_cur[c4.x >> 8], 1); p.sbuf_src[pp] = r4.x; p.sbuf_c[pp] = (unsigned char)(c4.x & 255);
                pp = atomicAdd(&sh_cur[c4.y >> 8], 1); p.sbuf_src[pp] = r4.y; p.sbuf_c[pp] = (unsigned char)(c4.y & 255);
                pp = atomicAdd(&sh_cur[c4.z >> 8], 1); p.sbuf_src[pp] = r4.z; p.sbuf_c[pp] = (unsigned char)(c4.z & 255);
                pp = atomicAdd(&sh_cur[c4.w >> 8], 1); p.sbuf_src[pp] = r4.w; p.sbuf_c[pp] = (unsigned char)(c4.w & 255);
            }
            int i = vend + tid;
            if (i < end) {
                int c = p.col[i];
                int pp = atomicAdd(&sh_cur[c >> 8], 1);
                p.sbuf_src[pp] = p.row[i];
                p.sbuf_c[pp] = (unsigned char)(c & 255);
            }
        }
    }
    grid.sync();

    // ---- P3: per-node degree (persisted in sh_lcnt) + dinv + per-bin node total ----
    if (bid < NBINS) {
        sh_lcnt[tid] = 0;
        __syncthreads();
        int beg = sh_base[bid], end = sh_base[bid + 1];  // persisted from P2
        for (int j = beg + tid; j < end; j += 256)
            atomicAdd(&sh_lcnt[p.sbuf_c[j]], 1);
        __syncthreads();
        int deg = sh_lcnt[tid];
        int node = bid * 256 + tid;
        if (node < N_NODES) p.dinv[node] = rsqrtf((float)deg + 1.0f);
        sh_s[tid] = deg;
        __syncthreads();
#pragma unroll
        for (int off = 128; off; off >>= 1) {
            if (tid < off) sh_s[tid] += sh_s[tid + off];
            __syncthreads();
        }
        if (tid == 0) p.nodeTot[bid] = sh_s[0];
    }
    grid.sync();

    // ---- P4: row_ptr + CSR (src,w) placement (nodeBase per-block in LDS) ----
    if (bid < NBINS) {
        int v = (tid < NBINS) ? p.nodeTot[tid] : 0;
        int excl = block_scan_excl(v, sh_s, nullptr);
        if (tid < NBINS) sh_nbase[tid] = excl;
        __syncthreads();
        int deg = sh_lcnt[tid];  // persisted from P3
        int lexcl = block_scan_excl(deg, sh_s, nullptr);
        sh_cur[tid] = lexcl;
        int base = sh_nbase[bid];
        int node = bid * 256 + tid;
        if (node < N_NODES) p.row_ptr[node] = base + lexcl;
        if (bid == 0 && tid == 0) p.row_ptr[N_NODES] = p.E;
        sh_dloc[tid] = (node < N_NODES) ? p.dinv[node] : 0.f;
        __syncthreads();
        int beg = sh_base[bid], end = sh_base[bid + 1];
        for (int j = beg + tid; j < end; j += 256) {
            int c = p.sbuf_c[j];
            int src = p.sbuf_src[j];
            int pos = atomicAdd(&sh_cur[c], 1);
            float w = p.dinv[src] * sh_dloc[c];
            p.csr_sw[base + pos] = make_int2(src, __float_as_int(w));
        }
    }
    grid.sync();

    // ---- layers ----
    gemm_phase<128, false, true>(p.hA, p.W0h, p.W0l, nullptr, p.h2, G);
    grid.sync();
    agg_phase(p.h2, p.row_ptr, p.csr_sw, p.dinv, p.b0, p.hA, G);
    grid.sync();
    gemm_phase<128, false, true>(p.hA, p.W1h, p.W1l, nullptr, p.h2, G);
    grid.sync();
    agg_phase(p.h2, p.row_ptr, p.csr_sw, p.dinv, p.b1, p.hA, G);
    grid.sync();
    gemm_phase<128, false, true>(p.hA, p.W2h, p.W2l, nullptr, p.h2, G);
    grid.sync();
    agg_phase(p.h2, p.row_ptr, p.csr_sw, p.dinv, p.b2, p.hA, G);
    grid.sync();
    gemm_phase<64, true, false>(p.hA, p.Wlh, p.Wll, p.bl, p.out, G);
}

extern "C" void kernel_launch(void* const* d_in, const int* in_sizes, int n_in,
                              void* d_out, int out_size, void* d_ws, size_t ws_size,
                              hipStream_t stream) {
    const int N = N_NODES;
    const int E = in_sizes[1] / 2;
    const int* ei = (const int*)d_in[1];

    char* ws = (char*)d_ws;
    auto alloc = [&](size_t bytes) {
        char* p = ws;
        ws += (bytes + 255) & ~(size_t)255;
        return p;
    };

    MegaParams mp;
    mp.x   = (const float*)d_in[0];
    mp.row = ei;
    mp.col = ei + E;
    mp.W0 = (const float*)d_in[2]; mp.b0 = (const float*)d_in[3];
    mp.W1 = (const float*)d_in[4]; mp.b1 = (const float*)d_in[5];
    mp.W2 = (const float*)d_in[6]; mp.b2 = (const float*)d_in[7];
    mp.Wl = (const float*)d_in[8]; mp.bl = (const float*)d_in[9];
    mp.out = (float*)d_out;
    mp.E = E;

    mp.hist     = (int*)alloc((size_t)NBINS * MAXG * 4);
    mp.hlocal   = (int*)alloc((size_t)NBINS * MAXG * 4);
    mp.binTot   = (int*)alloc((size_t)NBINS * 4);
    mp.nodeTot  = (int*)alloc((size_t)NBINS * 4);
    mp.sbuf_src = (int*)alloc((size_t)E * 4);
    mp.sbuf_c   = (unsigned char*)alloc((size_t)E);
    mp.row_ptr  = (int*)alloc((size_t)(N + 1) * 4);
    mp.dinv     = (float*)alloc((size_t)N * 4);
    mp.csr_sw   = (int2*)alloc((size_t)E * 8);
    mp.h2       = (__half*)alloc((size_t)N * HID * 2);
    mp.hA       = (__half*)alloc((size_t)N * HID * 2);
    mp.W0h = (__half*)alloc((size_t)HID * HID * 2);
    mp.W0l = (__half*)alloc((size_t)HID * HID * 2);
    mp.W1h = (__half*)alloc((size_t)HID * HID * 2);
    mp.W1l = (__half*)alloc((size_t)HID * HID * 2);
    mp.W2h = (__half*)alloc((size_t)HID * HID * 2);
    mp.W2l = (__half*)alloc((size_t)HID * HID * 2);
    mp.Wlh = (__half*)alloc((size_t)CLS * HID * 2);
    mp.Wll = (__half*)alloc((size_t)CLS * HID * 2);

    // occupancy-sized cooperative grid (deterministic across calls -> graph-safe)
    int maxB = 0;
    if (hipOccupancyMaxActiveBlocksPerMultiprocessor(&maxB, mega_kernel, 256, 0) != hipSuccess
        || maxB <= 0)
        maxB = 4;
    int G = maxB * 256;               // 256 CUs on MI355X
    if (G > MAXG) G = MAXG;
    if (G < 256) G = 256;
    mp.chunk = (((E + G - 1) / G) + 3) & ~3;

    void* args[] = { &mp };
    hipLaunchCooperativeKernel((void*)mega_kernel, dim3(G), dim3(256), args, 0, stream);
}

// Round 9
// 333.678 us; speedup vs baseline: 4.5384x; 4.5384x over previous
//
#include <hip/hip_runtime.h>
#include <hip/hip_fp16.h>

#define N_NODES 50000
#define HID 128
#define CLS 64

#define NBINS 196        // ceil(50000/256) node bins
#define NBLK 256         // hist/scatter blocks
#define LBUF_CAP 4096    // per-bin CSR staging (bin degree ~3265 + 14 sigma)
#define WTOT 57344       // 3*128*128 + 64*128 weight elements

typedef __attribute__((ext_vector_type(8))) _Float16 f16x8;
typedef __attribute__((ext_vector_type(4))) float f32x4;

// ---------------- K1: per-(block,bin) histogram + binTot atomics + W split -------
__global__ __launch_bounds__(256) void hist_wsplit_kernel(
    const int* __restrict__ col, int* __restrict__ hist, int* __restrict__ binTot,
    const float* __restrict__ W0, const float* __restrict__ W1,
    const float* __restrict__ W2, const float* __restrict__ Wl,
    __half* __restrict__ o0h, __half* __restrict__ o0l,
    __half* __restrict__ o1h, __half* __restrict__ o1l,
    __half* __restrict__ o2h, __half* __restrict__ o2l,
    __half* __restrict__ o3h, __half* __restrict__ o3l,
    int E, int chunk) {
    // W transpose/split: one element per thread (grid 256x256 = 65536 >= WTOT)
    int widx = blockIdx.x * 256 + threadIdx.x;
    if (widx < WTOT) {
        const float* W;
        __half *oh, *ol;
        int NCdim, local;
        if (widx < 16384)      { W = W0; oh = o0h; ol = o0l; NCdim = 128; local = widx; }
        else if (widx < 32768) { W = W1; oh = o1h; ol = o1l; NCdim = 128; local = widx - 16384; }
        else if (widx < 49152) { W = W2; oh = o2h; ol = o2l; NCdim = 128; local = widx - 32768; }
        else                   { W = Wl; oh = o3h; ol = o3l; NCdim = 64;  local = widx - 49152; }
        int nn = local >> 7;
        int k = local & 127;
        float v = W[(size_t)k * NCdim + nn];
        __half h = __float2half_rn(v);
        oh[local] = h;
        ol[local] = __float2half_rn(v - __half2float(h));
    }
    __shared__ int h[NBINS];
    for (int i = threadIdx.x; i < NBINS; i += 256) h[i] = 0;
    __syncthreads();
    int b = blockIdx.x;
    int beg = b * chunk;
    int end = min(E, beg + chunk);
    if (beg < end) {
        int vend = beg + ((end - beg) & ~3);
        for (int i = beg + threadIdx.x * 4; i < vend; i += 1024) {
            int4 c4 = *(const int4*)(col + i);
            atomicAdd(&h[c4.x >> 8], 1);
            atomicAdd(&h[c4.y >> 8], 1);
            atomicAdd(&h[c4.z >> 8], 1);
            atomicAdd(&h[c4.w >> 8], 1);
        }
        int i = vend + threadIdx.x;
        if (i < end) atomicAdd(&h[col[i] >> 8], 1);
    }
    __syncthreads();
    for (int i = threadIdx.x; i < NBINS; i += 256) {
        int v = h[i];
        hist[i * NBLK + b] = v;  // bin-major, block-minor
        if (v) atomicAdd(&binTot[i], v);
    }
}

// ---------------- K2: absolute per-(bin,block) cursors + binBase ----------------
__global__ __launch_bounds__(256) void binscan_kernel(const int* __restrict__ hist,
                                                      const int* __restrict__ binTot,
                                                      int* __restrict__ hlocal,
                                                      int* __restrict__ binBase, int E) {
    __shared__ int s[256];
    int i = blockIdx.x, t = threadIdx.x;
    // binBase = exclusive scan of binTot (196 entries), computed in-block
    int bv = (t < NBINS) ? binTot[t] : 0;
    s[t] = bv;
    __syncthreads();
#pragma unroll
    for (int off = 1; off < 256; off <<= 1) {
        int u = (t >= off) ? s[t - off] : 0;
        __syncthreads();
        s[t] += u;
        __syncthreads();
    }
    int myBase = (i == 0) ? 0 : s[i - 1];  // exclusive prefix for bin i
    if (t == i) binBase[i] = s[i] - bv;    // block i writes binBase[i]
    if (i == 0 && t == 0) binBase[NBINS] = E;
    __syncthreads();
    // absolute cursor for each scatter block: binBase + prefix of hist row i
    int v = hist[i * NBLK + t];
    s[t] = v;
    __syncthreads();
#pragma unroll
    for (int off = 1; off < 256; off <<= 1) {
        int u = (t >= off) ? s[t - off] : 0;
        __syncthreads();
        s[t] += u;
        __syncthreads();
    }
    hlocal[i * NBLK + t] = myBase + s[t] - v;
}

// ---------------- K3: scatter edges bin-sorted (src 4B + colLow 1B) ----------------
__global__ __launch_bounds__(256) void scatter_kernel(
    const int* __restrict__ row, const int* __restrict__ col,
    const int* __restrict__ hlocal,
    int* __restrict__ sbuf_src, unsigned char* __restrict__ sbuf_c,
    int E, int chunk) {
    __shared__ int cur[NBINS];
    int b = blockIdx.x;
    for (int i = threadIdx.x; i < NBINS; i += 256)
        cur[i] = hlocal[i * NBLK + b];
    __syncthreads();
    int beg = b * chunk;
    int end = min(E, beg + chunk);
    if (beg >= end) return;
    int vend = beg + ((end - beg) & ~3);
    for (int i = beg + threadIdx.x * 4; i < vend; i += 1024) {
        int4 c4 = *(const int4*)(col + i);
        int4 r4 = *(const int4*)(row + i);
        int p;
        p = atomicAdd(&cur[c4.x >> 8], 1); sbuf_src[p] = r4.x; sbuf_c[p] = (unsigned char)(c4.x & 255);
        p = atomicAdd(&cur[c4.y >> 8], 1); sbuf_src[p] = r4.y; sbuf_c[p] = (unsigned char)(c4.y & 255);
        p = atomicAdd(&cur[c4.z >> 8], 1); sbuf_src[p] = r4.z; sbuf_c[p] = (unsigned char)(c4.z & 255);
        p = atomicAdd(&cur[c4.w >> 8], 1); sbuf_src[p] = r4.w; sbuf_c[p] = (unsigned char)(c4.w & 255);
    }
    int i = vend + threadIdx.x;
    if (i < end) {
        int c = col[i];
        int p = atomicAdd(&cur[c >> 8], 1);
        sbuf_src[p] = row[i];
        sbuf_c[p] = (unsigned char)(c & 255);
    }
}

// ---------------- K4: count + dinv + row_ptr + CSR(src) place, all per bin --------
// nodeBase[i] == binBase[i]: CSR segment of bin i starts at its edge-sort offset.
__global__ __launch_bounds__(256) void csr_place_kernel(
    const int* __restrict__ binBase,
    const int* __restrict__ sbuf_src, const unsigned char* __restrict__ sbuf_c,
    float* __restrict__ dinv, int* __restrict__ row_ptr,
    int* __restrict__ csr_src, int n, int E) {
    __shared__ int lcnt[256];
    __shared__ int lcur[256];
    __shared__ int ss[256];
    __shared__ int lbuf[LBUF_CAP];
    int t = threadIdx.x, b = blockIdx.x;
    lcnt[t] = 0;
    __syncthreads();
    int beg = binBase[b], end = binBase[b + 1];
    for (int j = beg + t; j < end; j += 256)
        atomicAdd(&lcnt[sbuf_c[j]], 1);
    __syncthreads();
    int deg = lcnt[t];
    int node = b * 256 + t;
    if (node < n) dinv[node] = rsqrtf((float)deg + 1.0f);
    ss[t] = deg;
    __syncthreads();
#pragma unroll
    for (int off = 1; off < 256; off <<= 1) {
        int u = (t >= off) ? ss[t - off] : 0;
        __syncthreads();
        ss[t] += u;
        __syncthreads();
    }
    int excl = ss[t] - deg;
    lcur[t] = excl;
    int total = ss[255];
    if (node < n) row_ptr[node] = beg + excl;
    if (b == 0 && t == 0) row_ptr[n] = E;
    __syncthreads();
    for (int j = beg + t; j < end; j += 256) {
        int c = sbuf_c[j];
        int pos = atomicAdd(&lcur[c], 1);
        lbuf[pos] = sbuf_src[j];
    }
    __syncthreads();
    for (int j = t; j < total; j += 256) csr_src[beg + j] = lbuf[j];
}

// ---------------- f16 MFMA GEMM: C = A @ (Wh+Wl) (+bias), K=128 ----------------
// F32A: A is fp32 (layer 0 reads x directly), converted in-register.
template<int NC, bool ADD_BIAS, bool HALF_OUT, bool F32A>
__global__ __launch_bounds__(256) void mfma_gemm_f16(
    const void* __restrict__ Av, const __half* __restrict__ Bh,
    const __half* __restrict__ Bl, const float* __restrict__ bias,
    void* __restrict__ Cv, int M) {
    constexpr int NT = NC / 16;
    int lane = threadIdx.x & 63;
    int rowTile = blockIdx.x * 4 + (threadIdx.x >> 6);
    int m0 = rowTile << 4;
    if (m0 >= M) return;
    int mr = lane & 15;
    int kq = (lane >> 4) << 3;  // 0,8,16,24

    const __half* ah = F32A ? nullptr : (const __half*)Av + (size_t)(m0 + mr) * 128 + kq;
    const float*  af = F32A ? (const float*)Av + (size_t)(m0 + mr) * 128 + kq : nullptr;
    const __half* bh = Bh + (size_t)mr * 128 + kq;
    const __half* bl = Bl + (size_t)mr * 128 + kq;

    f32x4 acc[NT];
#pragma unroll
    for (int t = 0; t < NT; ++t) acc[t] = (f32x4){0.f, 0.f, 0.f, 0.f};

#pragma unroll
    for (int kc = 0; kc < 128; kc += 32) {
        f16x8 a;
        if (F32A) {
            float4 lo = *(const float4*)(af + kc);
            float4 hi = *(const float4*)(af + kc + 4);
            a[0] = (_Float16)lo.x; a[1] = (_Float16)lo.y;
            a[2] = (_Float16)lo.z; a[3] = (_Float16)lo.w;
            a[4] = (_Float16)hi.x; a[5] = (_Float16)hi.y;
            a[6] = (_Float16)hi.z; a[7] = (_Float16)hi.w;
        } else {
            a = *(const f16x8*)(ah + kc);
        }
#pragma unroll
        for (int t = 0; t < NT; ++t) {
            f16x8 wh = *(const f16x8*)(bh + (size_t)t * 16 * 128 + kc);
            f16x8 wl = *(const f16x8*)(bl + (size_t)t * 16 * 128 + kc);
            acc[t] = __builtin_amdgcn_mfma_f32_16x16x32_f16(a, wh, acc[t], 0, 0, 0);
            acc[t] = __builtin_amdgcn_mfma_f32_16x16x32_f16(a, wl, acc[t], 0, 0, 0);
        }
    }

    // C/D layout: col = lane&15, row = (lane>>4)*4 + reg
    int r0 = m0 + ((lane >> 4) << 2);
    int cc = lane & 15;
#pragma unroll
    for (int t = 0; t < NT; ++t) {
        float bsv = ADD_BIAS ? bias[t * 16 + cc] : 0.f;
#pragma unroll
        for (int r = 0; r < 4; ++r) {
            float val = acc[t][r] + bsv;
            size_t idx = (size_t)(r0 + r) * NC + t * 16 + cc;
            if (HALF_OUT)
                ((__half*)Cv)[idx] = __float2half_rn(val);
            else
                ((float*)Cv)[idx] = val;
        }
    }
}

// ---------------- aggregation: one wave per node, fp16 gather, src-only CSR -------
__global__ __launch_bounds__(256) void agg_kernel(
    const __half* __restrict__ h2, const int* __restrict__ row_ptr,
    const int* __restrict__ csr_src, const float* __restrict__ dinv,
    const float* __restrict__ bias, __half* __restrict__ outA, int n) {
    int wid = (blockIdx.x * 256 + threadIdx.x) >> 6;
    int lane = threadIdx.x & 63;
    if (wid >= n) return;
    int beg = row_ptr[wid];
    int end = row_ptr[wid + 1];
    float dv = dinv[wid];
    float ax = 0.f, ay = 0.f;
    int loff = lane << 1;
    for (int base = beg; base < end; base += 64) {
        int cnt = end - base;
        if (cnt > 64) cnt = 64;
        int msrc = 0;
        float mw = 0.f;
        if (lane < cnt) {
            msrc = csr_src[base + lane];
            mw = dinv[msrc] * dv;
        }
        int j = 0;
        for (; j + 8 <= cnt; j += 8) {
            int s0 = __shfl(msrc, j),     s1 = __shfl(msrc, j + 1);
            int s2 = __shfl(msrc, j + 2), s3 = __shfl(msrc, j + 3);
            int s4 = __shfl(msrc, j + 4), s5 = __shfl(msrc, j + 5);
            int s6 = __shfl(msrc, j + 6), s7 = __shfl(msrc, j + 7);
            float w0 = __shfl(mw, j),     w1 = __shfl(mw, j + 1);
            float w2 = __shfl(mw, j + 2), w3 = __shfl(mw, j + 3);
            float w4 = __shfl(mw, j + 4), w5 = __shfl(mw, j + 5);
            float w6 = __shfl(mw, j + 6), w7 = __shfl(mw, j + 7);
            float2 v0 = __half22float2(*(const __half2*)(h2 + ((size_t)s0 << 7) + loff));
            float2 v1 = __half22float2(*(const __half2*)(h2 + ((size_t)s1 << 7) + loff));
            float2 v2 = __half22float2(*(const __half2*)(h2 + ((size_t)s2 << 7) + loff));
            float2 v3 = __half22float2(*(const __half2*)(h2 + ((size_t)s3 << 7) + loff));
            float2 v4 = __half22float2(*(const __half2*)(h2 + ((size_t)s4 << 7) + loff));
            float2 v5 = __half22float2(*(const __half2*)(h2 + ((size_t)s5 << 7) + loff));
            float2 v6 = __half22float2(*(const __half2*)(h2 + ((size_t)s6 << 7) + loff));
            float2 v7 = __half22float2(*(const __half2*)(h2 + ((size_t)s7 << 7) + loff));
            ax = fmaf(v0.x, w0, ax); ay = fmaf(v0.y, w0, ay);
            ax = fmaf(v1.x, w1, ax); ay = fmaf(v1.y, w1, ay);
            ax = fmaf(v2.x, w2, ax); ay = fmaf(v2.y, w2, ay);
            ax = fmaf(v3.x, w3, ax); ay = fmaf(v3.y, w3, ay);
            ax = fmaf(v4.x, w4, ax); ay = fmaf(v4.y, w4, ay);
            ax = fmaf(v5.x, w5, ax); ay = fmaf(v5.y, w5, ay);
            ax = fmaf(v6.x, w6, ax); ay = fmaf(v6.y, w6, ay);
            ax = fmaf(v7.x, w7, ax); ay = fmaf(v7.y, w7, ay);
        }
        for (; j + 4 <= cnt; j += 4) {
            int s0 = __shfl(msrc, j),     s1 = __shfl(msrc, j + 1);
            int s2 = __shfl(msrc, j + 2), s3 = __shfl(msrc, j + 3);
            float w0 = __shfl(mw, j),     w1 = __shfl(mw, j + 1);
            float w2 = __shfl(mw, j + 2), w3 = __shfl(mw, j + 3);
            float2 v0 = __half22float2(*(const __half2*)(h2 + ((size_t)s0 << 7) + loff));
            float2 v1 = __half22float2(*(const __half2*)(h2 + ((size_t)s1 << 7) + loff));
            float2 v2 = __half22float2(*(const __half2*)(h2 + ((size_t)s2 << 7) + loff));
            float2 v3 = __half22float2(*(const __half2*)(h2 + ((size_t)s3 << 7) + loff));
            ax = fmaf(v0.x, w0, ax); ay = fmaf(v0.y, w0, ay);
            ax = fmaf(v1.x, w1, ax); ay = fmaf(v1.y, w1, ay);
            ax = fmaf(v2.x, w2, ax); ay = fmaf(v2.y, w2, ay);
            ax = fmaf(v3.x, w3, ax); ay = fmaf(v3.y, w3, ay);
        }
        for (; j < cnt; ++j) {
            int s = __shfl(msrc, j);
            float w = __shfl(mw, j);
            float2 v = __half22float2(*(const __half2*)(h2 + ((size_t)s << 7) + loff));
            ax = fmaf(v.x, w, ax); ay = fmaf(v.y, w, ay);
        }
    }
    float sn = dv * dv;
    float2 self = __half22float2(*(const __half2*)(h2 + ((size_t)wid << 7) + loff));
    float2 b = *(const float2*)(bias + loff);
    float ox = fmaxf(fmaf(self.x, sn, ax) + b.x, 0.f);
    float oy = fmaxf(fmaf(self.y, sn, ay) + b.y, 0.f);
    *(__half2*)(outA + ((size_t)wid << 7) + loff) = __float22half2_rn(make_float2(ox, oy));
}

extern "C" void kernel_launch(void* const* d_in, const int* in_sizes, int n_in,
                              void* d_out, int out_size, void* d_ws, size_t ws_size,
                              hipStream_t stream) {
    const float* x  = (const float*)d_in[0];
    const int* ei   = (const int*)d_in[1];
    const float* W0 = (const float*)d_in[2];
    const float* b0 = (const float*)d_in[3];
    const float* W1 = (const float*)d_in[4];
    const float* b1 = (const float*)d_in[5];
    const float* W2 = (const float*)d_in[6];
    const float* b2 = (const float*)d_in[7];
    const float* Wl = (const float*)d_in[8];
    const float* bl = (const float*)d_in[9];
    float* out = (float*)d_out;

    const int N = N_NODES;
    const int E = in_sizes[1] / 2;
    const int* row = ei;
    const int* col = ei + E;
    const int chunk = (((E + NBLK - 1) / NBLK) + 3) & ~3;  // 4-aligned chunks

    char* ws = (char*)d_ws;
    auto alloc = [&](size_t bytes) {
        char* p = ws;
        ws += (bytes + 255) & ~(size_t)255;
        return p;
    };
    int*   hist    = (int*)alloc((size_t)NBINS * NBLK * 4);
    int*   hlocal  = (int*)alloc((size_t)NBINS * NBLK * 4);
    int*   binTot  = (int*)alloc((size_t)NBINS * 4);
    int*   binBase = (int*)alloc((size_t)(NBINS + 1) * 4);
    int*   sbuf_src= (int*)alloc((size_t)E * 4);
    unsigned char* sbuf_c = (unsigned char*)alloc((size_t)E);
    int*   row_ptr = (int*)alloc((size_t)(N + 1) * 4);
    float* dinv    = (float*)alloc((size_t)N * 4);
    int*   csr_src = (int*)alloc((size_t)E * 4);
    __half* h2     = (__half*)alloc((size_t)N * HID * 2);  // GEMM out (gather source)
    __half* hA     = (__half*)alloc((size_t)N * HID * 2);  // agg out (next GEMM A)
    __half* Wt_h[4];
    __half* Wt_l[4];
    for (int i = 0; i < 3; ++i) {
        Wt_h[i] = (__half*)alloc((size_t)HID * HID * 2);
        Wt_l[i] = (__half*)alloc((size_t)HID * HID * 2);
    }
    Wt_h[3] = (__half*)alloc((size_t)CLS * HID * 2);
    Wt_l[3] = (__half*)alloc((size_t)CLS * HID * 2);

    hipMemsetAsync(binTot, 0, (size_t)NBINS * 4, stream);

    // CSR pipeline (4 kernels)
    hist_wsplit_kernel<<<NBLK, 256, 0, stream>>>(col, hist, binTot, W0, W1, W2, Wl,
        Wt_h[0], Wt_l[0], Wt_h[1], Wt_l[1], Wt_h[2], Wt_l[2], Wt_h[3], Wt_l[3], E, chunk);
    binscan_kernel<<<NBINS, 256, 0, stream>>>(hist, binTot, hlocal, binBase, E);
    scatter_kernel<<<NBLK, 256, 0, stream>>>(row, col, hlocal, sbuf_src, sbuf_c, E, chunk);
    csr_place_kernel<<<NBINS, 256, 0, stream>>>(binBase, sbuf_src, sbuf_c,
                                                dinv, row_ptr, csr_src, N, E);

    const int gemmBlocks = (N / 16 + 3) / 4;  // 782 blocks x 4 waves >= 3125 tiles
    const int aggBlocks  = (N + 3) / 4;

    // layer 0 (GEMM reads x fp32 directly)
    mfma_gemm_f16<128, false, true, true><<<gemmBlocks, 256, 0, stream>>>(x, Wt_h[0], Wt_l[0], nullptr, h2, N);
    agg_kernel<<<aggBlocks, 256, 0, stream>>>(h2, row_ptr, csr_src, dinv, b0, hA, N);
    // layer 1
    mfma_gemm_f16<128, false, true, false><<<gemmBlocks, 256, 0, stream>>>(hA, Wt_h[1], Wt_l[1], nullptr, h2, N);
    agg_kernel<<<aggBlocks, 256, 0, stream>>>(h2, row_ptr, csr_src, dinv, b1, hA, N);
    // layer 2
    mfma_gemm_f16<128, false, true, false><<<gemmBlocks, 256, 0, stream>>>(hA, Wt_h[2], Wt_l[2], nullptr, h2, N);
    agg_kernel<<<aggBlocks, 256, 0, stream>>>(h2, row_ptr, csr_src, dinv, b2, hA, N);
    // classifier head
    mfma_gemm_f16<64, true, false, false><<<gemmBlocks, 256, 0, stream>>>(hA, Wt_h[3], Wt_l[3], bl, out, N);
}

// Round 10
// 318.165 us; speedup vs baseline: 4.7597x; 1.0488x over previous
//
#include <hip/hip_runtime.h>
#include <hip/hip_fp16.h>

#define N_NODES 50000
#define HID 128
#define CLS 64

#define NBINS 196        // ceil(50000/256) node bins
#define NBLK 256         // hist/scatter blocks
#define LBUF_CAP 4096    // per-bin CSR staging (bin degree ~3277 + 14 sigma)
#define WTOT 57344       // 3*128*128 + 64*128 weight elements
#define GEMM0_BLOCKS 782 // ceil(3125 tiles / 4 waves)

typedef __attribute__((ext_vector_type(8))) _Float16 f16x8;
typedef __attribute__((ext_vector_type(4))) float f32x4;

// ---------------- K1: per-(block,bin) histogram + W split ----------------
__global__ __launch_bounds__(256) void hist_wsplit_kernel(
    const int* __restrict__ col, int* __restrict__ hist,
    const float* __restrict__ W0, const float* __restrict__ W1,
    const float* __restrict__ W2, const float* __restrict__ Wl,
    __half* __restrict__ o0h, __half* __restrict__ o0l,
    __half* __restrict__ o1h, __half* __restrict__ o1l,
    __half* __restrict__ o2h, __half* __restrict__ o2l,
    __half* __restrict__ o3h, __half* __restrict__ o3l,
    int E, int chunk) {
    int widx = blockIdx.x * 256 + threadIdx.x;
    if (widx < WTOT) {
        const float* W;
        __half *oh, *ol;
        int NCdim, local;
        if (widx < 16384)      { W = W0; oh = o0h; ol = o0l; NCdim = 128; local = widx; }
        else if (widx < 32768) { W = W1; oh = o1h; ol = o1l; NCdim = 128; local = widx - 16384; }
        else if (widx < 49152) { W = W2; oh = o2h; ol = o2l; NCdim = 128; local = widx - 32768; }
        else                   { W = Wl; oh = o3h; ol = o3l; NCdim = 64;  local = widx - 49152; }
        int nn = local >> 7;
        int k = local & 127;
        float v = W[(size_t)k * NCdim + nn];
        __half h = __float2half_rn(v);
        oh[local] = h;
        ol[local] = __float2half_rn(v - __half2float(h));
    }
    __shared__ int h[NBINS];
    for (int i = threadIdx.x; i < NBINS; i += 256) h[i] = 0;
    __syncthreads();
    int b = blockIdx.x;
    int beg = b * chunk;
    int end = min(E, beg + chunk);
    if (beg < end) {
        int vend = beg + ((end - beg) & ~3);
        for (int i = beg + threadIdx.x * 4; i < vend; i += 1024) {
            int4 c4 = *(const int4*)(col + i);
            atomicAdd(&h[c4.x >> 8], 1);
            atomicAdd(&h[c4.y >> 8], 1);
            atomicAdd(&h[c4.z >> 8], 1);
            atomicAdd(&h[c4.w >> 8], 1);
        }
        int i = vend + threadIdx.x;
        if (i < end) atomicAdd(&h[col[i] >> 8], 1);
    }
    __syncthreads();
    for (int i = threadIdx.x; i < NBINS; i += 256)
        hist[i * NBLK + b] = h[i];  // bin-major, block-minor
}

// ---------------- K2: scatter (self-computed cursors; binBase published) ----------
__global__ __launch_bounds__(256) void scatter_kernel(
    const int* __restrict__ row, const int* __restrict__ col,
    const int* __restrict__ hist, int* __restrict__ binBase_g,
    int* __restrict__ sbuf_src, unsigned char* __restrict__ sbuf_c,
    int E, int chunk) {
    __shared__ int sTot[256];
    __shared__ int cur[NBINS];
    int b = blockIdx.x, t = threadIdx.x;
    int partial = 0, total = 0;
    if (t < NBINS) {
        const int4* r4 = (const int4*)(hist + t * NBLK);
        int nb4 = b >> 2, rem = b & 3;
        for (int j = 0; j < NBLK / 4; ++j) {
            int4 v = r4[j];
            int s = v.x + v.y + v.z + v.w;
            total += s;
            if (j < nb4) partial += s;
            else if (j == nb4) {
                if (rem > 0) partial += v.x;
                if (rem > 1) partial += v.y;
                if (rem > 2) partial += v.z;
            }
        }
    }
    sTot[t] = (t < NBINS) ? total : 0;
    __syncthreads();
#pragma unroll
    for (int off = 1; off < 256; off <<= 1) {
        int u = (t >= off) ? sTot[t - off] : 0;
        __syncthreads();
        sTot[t] += u;
        __syncthreads();
    }
    int myBase = sTot[t] - total;  // exclusive scan value for bin t
    if (t < NBINS) cur[t] = myBase + partial;
    if (b == 0) {
        if (t < NBINS) binBase_g[t] = myBase;
        if (t == 0) binBase_g[NBINS] = E;
    }
    __syncthreads();
    int beg = b * chunk;
    int end = min(E, beg + chunk);
    if (beg >= end) return;
    int vend = beg + ((end - beg) & ~3);
    for (int i = beg + t * 4; i < vend; i += 1024) {
        int4 c4 = *(const int4*)(col + i);
        int4 r4 = *(const int4*)(row + i);
        int p;
        p = atomicAdd(&cur[c4.x >> 8], 1); sbuf_src[p] = r4.x; sbuf_c[p] = (unsigned char)(c4.x & 255);
        p = atomicAdd(&cur[c4.y >> 8], 1); sbuf_src[p] = r4.y; sbuf_c[p] = (unsigned char)(c4.y & 255);
        p = atomicAdd(&cur[c4.z >> 8], 1); sbuf_src[p] = r4.z; sbuf_c[p] = (unsigned char)(c4.z & 255);
        p = atomicAdd(&cur[c4.w >> 8], 1); sbuf_src[p] = r4.w; sbuf_c[p] = (unsigned char)(c4.w & 255);
    }
    int i = vend + t;
    if (i < end) {
        int c = col[i];
        int p = atomicAdd(&cur[c >> 8], 1);
        sbuf_src[p] = row[i];
        sbuf_c[p] = (unsigned char)(c & 255);
    }
}

// ---------------- GEMM body (shared by fused K3 and standalone) ----------------
template<int NC, bool ADD_BIAS, bool HALF_OUT, bool F32A>
__device__ __forceinline__ void gemm_body(
    const void* __restrict__ Av, const __half* __restrict__ Bh,
    const __half* __restrict__ Bl, const float* __restrict__ bias,
    void* __restrict__ Cv, int M, int rowTile) {
    constexpr int NT = NC / 16;
    int lane = threadIdx.x & 63;
    int m0 = rowTile << 4;
    if (m0 >= M) return;
    int mr = lane & 15;
    int kq = (lane >> 4) << 3;  // 0,8,16,24

    const __half* ah = F32A ? nullptr : (const __half*)Av + (size_t)(m0 + mr) * 128 + kq;
    const float*  af = F32A ? (const float*)Av + (size_t)(m0 + mr) * 128 + kq : nullptr;
    const __half* bh = Bh + (size_t)mr * 128 + kq;
    const __half* bl = Bl + (size_t)mr * 128 + kq;

    f32x4 acc[NT];
#pragma unroll
    for (int t = 0; t < NT; ++t) acc[t] = (f32x4){0.f, 0.f, 0.f, 0.f};

#pragma unroll
    for (int kc = 0; kc < 128; kc += 32) {
        f16x8 a;
        if (F32A) {
            float4 lo = *(const float4*)(af + kc);
            float4 hi = *(const float4*)(af + kc + 4);
            a[0] = (_Float16)lo.x; a[1] = (_Float16)lo.y;
            a[2] = (_Float16)lo.z; a[3] = (_Float16)lo.w;
            a[4] = (_Float16)hi.x; a[5] = (_Float16)hi.y;
            a[6] = (_Float16)hi.z; a[7] = (_Float16)hi.w;
        } else {
            a = *(const f16x8*)(ah + kc);
        }
#pragma unroll
        for (int t = 0; t < NT; ++t) {
            f16x8 wh = *(const f16x8*)(bh + (size_t)t * 16 * 128 + kc);
            f16x8 wl = *(const f16x8*)(bl + (size_t)t * 16 * 128 + kc);
            acc[t] = __builtin_amdgcn_mfma_f32_16x16x32_f16(a, wh, acc[t], 0, 0, 0);
            acc[t] = __builtin_amdgcn_mfma_f32_16x16x32_f16(a, wl, acc[t], 0, 0, 0);
        }
    }

    // C/D layout: col = lane&15, row = (lane>>4)*4 + reg
    int r0 = m0 + ((lane >> 4) << 2);
    int cc = lane & 15;
#pragma unroll
    for (int t = 0; t < NT; ++t) {
        float bsv = ADD_BIAS ? bias[t * 16 + cc] : 0.f;
#pragma unroll
        for (int r = 0; r < 4; ++r) {
            float val = acc[t][r] + bsv;
            size_t idx = (size_t)(r0 + r) * NC + t * 16 + cc;
            if (HALF_OUT)
                ((__half*)Cv)[idx] = __float2half_rn(val);
            else
                ((float*)Cv)[idx] = val;
        }
    }
}

template<int NC, bool ADD_BIAS, bool HALF_OUT, bool F32A>
__global__ __launch_bounds__(256) void mfma_gemm_f16(
    const void* __restrict__ Av, const __half* __restrict__ Bh,
    const __half* __restrict__ Bl, const float* __restrict__ bias,
    void* __restrict__ Cv, int M) {
    gemm_body<NC, ADD_BIAS, HALF_OUT, F32A>(Av, Bh, Bl, bias, Cv, M,
                                            blockIdx.x * 4 + (threadIdx.x >> 6));
}

// ---------------- K3: fused csr_place (blocks < NBINS) + GEMM-0 (rest) ------------
__global__ __launch_bounds__(256) void csrplace_gemm0_kernel(
    const int* __restrict__ binBase,
    const int* __restrict__ sbuf_src, const unsigned char* __restrict__ sbuf_c,
    float* __restrict__ dinv, int* __restrict__ row_ptr, int* __restrict__ csr_src,
    const float* __restrict__ x, const __half* __restrict__ W0h,
    const __half* __restrict__ W0l, __half* __restrict__ h2, int n, int E) {
    __shared__ int lcnt[256];
    __shared__ int lcur[256];
    __shared__ int ss[256];
    __shared__ int lbuf[LBUF_CAP];
    int b = blockIdx.x;
    if (b >= NBINS) {
        gemm_body<128, false, true, true>(x, W0h, W0l, nullptr, h2, n,
                                          (b - NBINS) * 4 + (threadIdx.x >> 6));
        return;
    }
    int t = threadIdx.x;
    lcnt[t] = 0;
    __syncthreads();
    int beg = binBase[b], end = binBase[b + 1];
    for (int j = beg + t; j < end; j += 256)
        atomicAdd(&lcnt[sbuf_c[j]], 1);
    __syncthreads();
    int deg = lcnt[t];
    int node = b * 256 + t;
    if (node < n) dinv[node] = rsqrtf((float)deg + 1.0f);
    ss[t] = deg;
    __syncthreads();
#pragma unroll
    for (int off = 1; off < 256; off <<= 1) {
        int u = (t >= off) ? ss[t - off] : 0;
        __syncthreads();
        ss[t] += u;
        __syncthreads();
    }
    int excl = ss[t] - deg;
    lcur[t] = excl;
    int total = ss[255];
    if (node < n) row_ptr[node] = beg + excl;
    if (b == 0 && t == 0) row_ptr[n] = E;
    __syncthreads();
    for (int j = beg + t; j < end; j += 256) {
        int c = sbuf_c[j];
        int pos = atomicAdd(&lcur[c], 1);
        lbuf[pos] = sbuf_src[j];
    }
    __syncthreads();
    for (int j = t; j < total; j += 256) csr_src[beg + j] = lbuf[j];
}

// ---------------- aggregation: one wave per node, fp16 gather, src-only CSR -------
__global__ __launch_bounds__(256) void agg_kernel(
    const __half* __restrict__ h2, const int* __restrict__ row_ptr,
    const int* __restrict__ csr_src, const float* __restrict__ dinv,
    const float* __restrict__ bias, __half* __restrict__ outA, int n) {
    int wid = (blockIdx.x * 256 + threadIdx.x) >> 6;
    int lane = threadIdx.x & 63;
    if (wid >= n) return;
    int beg = row_ptr[wid];
    int end = row_ptr[wid + 1];
    float dv = dinv[wid];
    float ax = 0.f, ay = 0.f;
    int loff = lane << 1;
    for (int base = beg; base < end; base += 64) {
        int cnt = end - base;
        if (cnt > 64) cnt = 64;
        int msrc = 0;
        float mw = 0.f;
        if (lane < cnt) {
            msrc = csr_src[base + lane];
            mw = dinv[msrc] * dv;
        }
        int j = 0;
        for (; j + 8 <= cnt; j += 8) {
            int s0 = __shfl(msrc, j),     s1 = __shfl(msrc, j + 1);
            int s2 = __shfl(msrc, j + 2), s3 = __shfl(msrc, j + 3);
            int s4 = __shfl(msrc, j + 4), s5 = __shfl(msrc, j + 5);
            int s6 = __shfl(msrc, j + 6), s7 = __shfl(msrc, j + 7);
            float w0 = __shfl(mw, j),     w1 = __shfl(mw, j + 1);
            float w2 = __shfl(mw, j + 2), w3 = __shfl(mw, j + 3);
            float w4 = __shfl(mw, j + 4), w5 = __shfl(mw, j + 5);
            float w6 = __shfl(mw, j + 6), w7 = __shfl(mw, j + 7);
            float2 v0 = __half22float2(*(const __half2*)(h2 + ((size_t)s0 << 7) + loff));
            float2 v1 = __half22float2(*(const __half2*)(h2 + ((size_t)s1 << 7) + loff));
            float2 v2 = __half22float2(*(const __half2*)(h2 + ((size_t)s2 << 7) + loff));
            float2 v3 = __half22float2(*(const __half2*)(h2 + ((size_t)s3 << 7) + loff));
            float2 v4 = __half22float2(*(const __half2*)(h2 + ((size_t)s4 << 7) + loff));
            float2 v5 = __half22float2(*(const __half2*)(h2 + ((size_t)s5 << 7) + loff));
            float2 v6 = __half22float2(*(const __half2*)(h2 + ((size_t)s6 << 7) + loff));
            float2 v7 = __half22float2(*(const __half2*)(h2 + ((size_t)s7 << 7) + loff));
            ax = fmaf(v0.x, w0, ax); ay = fmaf(v0.y, w0, ay);
            ax = fmaf(v1.x, w1, ax); ay = fmaf(v1.y, w1, ay);
            ax = fmaf(v2.x, w2, ax); ay = fmaf(v2.y, w2, ay);
            ax = fmaf(v3.x, w3, ax); ay = fmaf(v3.y, w3, ay);
            ax = fmaf(v4.x, w4, ax); ay = fmaf(v4.y, w4, ay);
            ax = fmaf(v5.x, w5, ax); ay = fmaf(v5.y, w5, ay);
            ax = fmaf(v6.x, w6, ax); ay = fmaf(v6.y, w6, ay);
            ax = fmaf(v7.x, w7, ax); ay = fmaf(v7.y, w7, ay);
        }
        for (; j + 4 <= cnt; j += 4) {
            int s0 = __shfl(msrc, j),     s1 = __shfl(msrc, j + 1);
            int s2 = __shfl(msrc, j + 2), s3 = __shfl(msrc, j + 3);
            float w0 = __shfl(mw, j),     w1 = __shfl(mw, j + 1);
            float w2 = __shfl(mw, j + 2), w3 = __shfl(mw, j + 3);
            float2 v0 = __half22float2(*(const __half2*)(h2 + ((size_t)s0 << 7) + loff));
            float2 v1 = __half22float2(*(const __half2*)(h2 + ((size_t)s1 << 7) + loff));
            float2 v2 = __half22float2(*(const __half2*)(h2 + ((size_t)s2 << 7) + loff));
            float2 v3 = __half22float2(*(const __half2*)(h2 + ((size_t)s3 << 7) + loff));
            ax = fmaf(v0.x, w0, ax); ay = fmaf(v0.y, w0, ay);
            ax = fmaf(v1.x, w1, ax); ay = fmaf(v1.y, w1, ay);
            ax = fmaf(v2.x, w2, ax); ay = fmaf(v2.y, w2, ay);
            ax = fmaf(v3.x, w3, ax); ay = fmaf(v3.y, w3, ay);
        }
        for (; j < cnt; ++j) {
            int s = __shfl(msrc, j);
            float w = __shfl(mw, j);
            float2 v = __half22float2(*(const __half2*)(h2 + ((size_t)s << 7) + loff));
            ax = fmaf(v.x, w, ax); ay = fmaf(v.y, w, ay);
        }
    }
    float sn = dv * dv;
    float2 self = __half22float2(*(const __half2*)(h2 + ((size_t)wid << 7) + loff));
    float2 b = *(const float2*)(bias + loff);
    float ox = fmaxf(fmaf(self.x, sn, ax) + b.x, 0.f);
    float oy = fmaxf(fmaf(self.y, sn, ay) + b.y, 0.f);
    *(__half2*)(outA + ((size_t)wid << 7) + loff) = __float22half2_rn(make_float2(ox, oy));
}

extern "C" void kernel_launch(void* const* d_in, const int* in_sizes, int n_in,
                              void* d_out, int out_size, void* d_ws, size_t ws_size,
                              hipStream_t stream) {
    const float* x  = (const float*)d_in[0];
    const int* ei   = (const int*)d_in[1];
    const float* W0 = (const float*)d_in[2];
    const float* b0 = (const float*)d_in[3];
    const float* W1 = (const float*)d_in[4];
    const float* b1 = (const float*)d_in[5];
    const float* W2 = (const float*)d_in[6];
    const float* b2 = (const float*)d_in[7];
    const float* Wl = (const float*)d_in[8];
    const float* bl = (const float*)d_in[9];
    float* out = (float*)d_out;

    const int N = N_NODES;
    const int E = in_sizes[1] / 2;
    const int* row = ei;
    const int* col = ei + E;
    const int chunk = (((E + NBLK - 1) / NBLK) + 3) & ~3;  // 4-aligned chunks

    char* ws = (char*)d_ws;
    auto alloc = [&](size_t bytes) {
        char* p = ws;
        ws += (bytes + 255) & ~(size_t)255;
        return p;
    };
    int*   hist    = (int*)alloc((size_t)NBINS * NBLK * 4);
    int*   binBase = (int*)alloc((size_t)(NBINS + 1) * 4);
    int*   sbuf_src= (int*)alloc((size_t)E * 4);
    unsigned char* sbuf_c = (unsigned char*)alloc((size_t)E);
    int*   row_ptr = (int*)alloc((size_t)(N + 1) * 4);
    float* dinv    = (float*)alloc((size_t)N * 4);
    int*   csr_src = (int*)alloc((size_t)E * 4);
    __half* h2     = (__half*)alloc((size_t)N * HID * 2);  // GEMM out (gather source)
    __half* hA     = (__half*)alloc((size_t)N * HID * 2);  // agg out (next GEMM A)
    __half* Wt_h[4];
    __half* Wt_l[4];
    for (int i = 0; i < 3; ++i) {
        Wt_h[i] = (__half*)alloc((size_t)HID * HID * 2);
        Wt_l[i] = (__half*)alloc((size_t)HID * HID * 2);
    }
    Wt_h[3] = (__half*)alloc((size_t)CLS * HID * 2);
    Wt_l[3] = (__half*)alloc((size_t)CLS * HID * 2);

    // K1: histogram + weight split
    hist_wsplit_kernel<<<NBLK, 256, 0, stream>>>(col, hist, W0, W1, W2, Wl,
        Wt_h[0], Wt_l[0], Wt_h[1], Wt_l[1], Wt_h[2], Wt_l[2], Wt_h[3], Wt_l[3], E, chunk);
    // K2: bin-sorted scatter (self-computed cursors)
    scatter_kernel<<<NBLK, 256, 0, stream>>>(row, col, hist, binBase, sbuf_src, sbuf_c, E, chunk);
    // K3: CSR placement fused with GEMM-0 (independent workloads)
    csrplace_gemm0_kernel<<<NBINS + GEMM0_BLOCKS, 256, 0, stream>>>(
        binBase, sbuf_src, sbuf_c, dinv, row_ptr, csr_src,
        x, Wt_h[0], Wt_l[0], h2, N, E);

    const int gemmBlocks = GEMM0_BLOCKS;
    const int aggBlocks  = (N + 3) / 4;

    agg_kernel<<<aggBlocks, 256, 0, stream>>>(h2, row_ptr, csr_src, dinv, b0, hA, N);
    mfma_gemm_f16<128, false, true, false><<<gemmBlocks, 256, 0, stream>>>(hA, Wt_h[1], Wt_l[1], nullptr, h2, N);
    agg_kernel<<<aggBlocks, 256, 0, stream>>>(h2, row_ptr, csr_src, dinv, b1, hA, N);
    mfma_gemm_f16<128, false, true, false><<<gemmBlocks, 256, 0, stream>>>(hA, Wt_h[2], Wt_l[2], nullptr, h2, N);
    agg_kernel<<<aggBlocks, 256, 0, stream>>>(h2, row_ptr, csr_src, dinv, b2, hA, N);
    mfma_gemm_f16<64, true, false, false><<<gemmBlocks, 256, 0, stream>>>(hA, Wt_h[3], Wt_l[3], bl, out, N);
}

// Round 11
// 280.995 us; speedup vs baseline: 5.3893x; 1.1323x over previous
//
#include <hip/hip_runtime.h>
#include <hip/hip_fp16.h>

#define N_NODES 50000
#define HID 128
#define CLS 64

#define NBINS 196        // ceil(50000/256) node bins
#define NBLK 256         // hist/scatter blocks
#define LBUF_CAP 4096    // per-bin CSR staging (bin degree ~3277 + 14 sigma)
#define WTOT 57344       // 3*128*128 + 64*128 weight elements
#define GEMM0_BLOCKS 782 // ceil(3125 tiles / 4 waves)
#define AROW 136         // LDS row stride (128 + 8 pad -> 2-way bank aliasing, free)

typedef __attribute__((ext_vector_type(8))) _Float16 f16x8;
typedef __attribute__((ext_vector_type(4))) float f32x4;

// ---------------- K1: per-(block,bin) histogram + W split ----------------
__global__ __launch_bounds__(256) void hist_wsplit_kernel(
    const int* __restrict__ col, int* __restrict__ hist,
    const float* __restrict__ W0, const float* __restrict__ W1,
    const float* __restrict__ W2, const float* __restrict__ Wl,
    __half* __restrict__ o0h, __half* __restrict__ o0l,
    __half* __restrict__ o1h, __half* __restrict__ o1l,
    __half* __restrict__ o2h, __half* __restrict__ o2l,
    __half* __restrict__ o3h, __half* __restrict__ o3l,
    int E, int chunk) {
    int widx = blockIdx.x * 256 + threadIdx.x;
    if (widx < WTOT) {
        const float* W;
        __half *oh, *ol;
        int NCdim, local;
        if (widx < 16384)      { W = W0; oh = o0h; ol = o0l; NCdim = 128; local = widx; }
        else if (widx < 32768) { W = W1; oh = o1h; ol = o1l; NCdim = 128; local = widx - 16384; }
        else if (widx < 49152) { W = W2; oh = o2h; ol = o2l; NCdim = 128; local = widx - 32768; }
        else                   { W = Wl; oh = o3h; ol = o3l; NCdim = 64;  local = widx - 49152; }
        int nn = local >> 7;
        int k = local & 127;
        float v = W[(size_t)k * NCdim + nn];
        __half h = __float2half_rn(v);
        oh[local] = h;
        ol[local] = __float2half_rn(v - __half2float(h));
    }
    __shared__ int h[NBINS];
    for (int i = threadIdx.x; i < NBINS; i += 256) h[i] = 0;
    __syncthreads();
    int b = blockIdx.x;
    int beg = b * chunk;
    int end = min(E, beg + chunk);
    if (beg < end) {
        int vend = beg + ((end - beg) & ~3);
        for (int i = beg + threadIdx.x * 4; i < vend; i += 1024) {
            int4 c4 = *(const int4*)(col + i);
            atomicAdd(&h[c4.x >> 8], 1);
            atomicAdd(&h[c4.y >> 8], 1);
            atomicAdd(&h[c4.z >> 8], 1);
            atomicAdd(&h[c4.w >> 8], 1);
        }
        int i = vend + threadIdx.x;
        if (i < end) atomicAdd(&h[col[i] >> 8], 1);
    }
    __syncthreads();
    for (int i = threadIdx.x; i < NBINS; i += 256)
        hist[i * NBLK + b] = h[i];  // bin-major, block-minor
}

// ---------------- K2: scatter (self-computed cursors; binBase published) ----------
__global__ __launch_bounds__(256) void scatter_kernel(
    const int* __restrict__ row, const int* __restrict__ col,
    const int* __restrict__ hist, int* __restrict__ binBase_g,
    int* __restrict__ sbuf_src, unsigned char* __restrict__ sbuf_c,
    int E, int chunk) {
    __shared__ int sTot[256];
    __shared__ int cur[NBINS];
    int b = blockIdx.x, t = threadIdx.x;
    int partial = 0, total = 0;
    if (t < NBINS) {
        const int4* r4 = (const int4*)(hist + t * NBLK);
        int nb4 = b >> 2, rem = b & 3;
        for (int j = 0; j < NBLK / 4; ++j) {
            int4 v = r4[j];
            int s = v.x + v.y + v.z + v.w;
            total += s;
            if (j < nb4) partial += s;
            else if (j == nb4) {
                if (rem > 0) partial += v.x;
                if (rem > 1) partial += v.y;
                if (rem > 2) partial += v.z;
            }
        }
    }
    sTot[t] = (t < NBINS) ? total : 0;
    __syncthreads();
#pragma unroll
    for (int off = 1; off < 256; off <<= 1) {
        int u = (t >= off) ? sTot[t - off] : 0;
        __syncthreads();
        sTot[t] += u;
        __syncthreads();
    }
    int myBase = sTot[t] - total;  // exclusive scan value for bin t
    if (t < NBINS) cur[t] = myBase + partial;
    if (b == 0) {
        if (t < NBINS) binBase_g[t] = myBase;
        if (t == 0) binBase_g[NBINS] = E;
    }
    __syncthreads();
    int beg = b * chunk;
    int end = min(E, beg + chunk);
    if (beg >= end) return;
    int vend = beg + ((end - beg) & ~3);
    for (int i = beg + t * 4; i < vend; i += 1024) {
        int4 c4 = *(const int4*)(col + i);
        int4 r4 = *(const int4*)(row + i);
        int p;
        p = atomicAdd(&cur[c4.x >> 8], 1); sbuf_src[p] = r4.x; sbuf_c[p] = (unsigned char)(c4.x & 255);
        p = atomicAdd(&cur[c4.y >> 8], 1); sbuf_src[p] = r4.y; sbuf_c[p] = (unsigned char)(c4.y & 255);
        p = atomicAdd(&cur[c4.z >> 8], 1); sbuf_src[p] = r4.z; sbuf_c[p] = (unsigned char)(c4.z & 255);
        p = atomicAdd(&cur[c4.w >> 8], 1); sbuf_src[p] = r4.w; sbuf_c[p] = (unsigned char)(c4.w & 255);
    }
    int i = vend + t;
    if (i < end) {
        int c = col[i];
        int p = atomicAdd(&cur[c >> 8], 1);
        sbuf_src[p] = row[i];
        sbuf_c[p] = (unsigned char)(c & 255);
    }
}

// ---------------- GEMM body for gemm-0 (A = x fp32, in-register convert) ----------
__device__ __forceinline__ void gemm0_body(
    const float* __restrict__ x, const __half* __restrict__ Bh,
    const __half* __restrict__ Bl, __half* __restrict__ C, int M, int rowTile) {
    constexpr int NT = 8;
    int lane = threadIdx.x & 63;
    int m0 = rowTile << 4;
    if (m0 >= M) return;
    int mr = lane & 15;
    int kq = (lane >> 4) << 3;

    const float*  af = x + (size_t)(m0 + mr) * 128 + kq;
    const __half* bh = Bh + (size_t)mr * 128 + kq;
    const __half* bl = Bl + (size_t)mr * 128 + kq;

    f32x4 acc[NT];
#pragma unroll
    for (int t = 0; t < NT; ++t) acc[t] = (f32x4){0.f, 0.f, 0.f, 0.f};
#pragma unroll
    for (int kc = 0; kc < 128; kc += 32) {
        float4 lo = *(const float4*)(af + kc);
        float4 hi = *(const float4*)(af + kc + 4);
        f16x8 a;
        a[0] = (_Float16)lo.x; a[1] = (_Float16)lo.y;
        a[2] = (_Float16)lo.z; a[3] = (_Float16)lo.w;
        a[4] = (_Float16)hi.x; a[5] = (_Float16)hi.y;
        a[6] = (_Float16)hi.z; a[7] = (_Float16)hi.w;
#pragma unroll
        for (int t = 0; t < NT; ++t) {
            f16x8 wh = *(const f16x8*)(bh + (size_t)t * 16 * 128 + kc);
            f16x8 wl = *(const f16x8*)(bl + (size_t)t * 16 * 128 + kc);
            acc[t] = __builtin_amdgcn_mfma_f32_16x16x32_f16(a, wh, acc[t], 0, 0, 0);
            acc[t] = __builtin_amdgcn_mfma_f32_16x16x32_f16(a, wl, acc[t], 0, 0, 0);
        }
    }
    int r0 = m0 + ((lane >> 4) << 2);
    int cc = lane & 15;
#pragma unroll
    for (int t = 0; t < NT; ++t)
#pragma unroll
        for (int r = 0; r < 4; ++r)
            C[(size_t)(r0 + r) * 128 + t * 16 + cc] =
                __float2half_rn(acc[t][r]);
}

// ---------------- K3: fused csr_place (blocks < NBINS) + GEMM-0 (rest) ------------
__global__ __launch_bounds__(256) void csrplace_gemm0_kernel(
    const int* __restrict__ binBase,
    const int* __restrict__ sbuf_src, const unsigned char* __restrict__ sbuf_c,
    float* __restrict__ dinv, int* __restrict__ row_ptr, int* __restrict__ csr_src,
    const float* __restrict__ x, const __half* __restrict__ W0h,
    const __half* __restrict__ W0l, __half* __restrict__ h2, int n, int E) {
    __shared__ int lcnt[256];
    __shared__ int lcur[256];
    __shared__ int ss[256];
    __shared__ int lbuf[LBUF_CAP];
    int b = blockIdx.x;
    if (b >= NBINS) {
        gemm0_body(x, W0h, W0l, h2, n, (b - NBINS) * 4 + (threadIdx.x >> 6));
        return;
    }
    int t = threadIdx.x;
    lcnt[t] = 0;
    __syncthreads();
    int beg = binBase[b], end = binBase[b + 1];
    for (int j = beg + t; j < end; j += 256)
        atomicAdd(&lcnt[sbuf_c[j]], 1);
    __syncthreads();
    int deg = lcnt[t];
    int node = b * 256 + t;
    if (node < n) dinv[node] = rsqrtf((float)deg + 1.0f);
    ss[t] = deg;
    __syncthreads();
#pragma unroll
    for (int off = 1; off < 256; off <<= 1) {
        int u = (t >= off) ? ss[t - off] : 0;
        __syncthreads();
        ss[t] += u;
        __syncthreads();
    }
    int excl = ss[t] - deg;
    lcur[t] = excl;
    int total = ss[255];
    if (node < n) row_ptr[node] = beg + excl;
    if (b == 0 && t == 0) row_ptr[n] = E;
    __syncthreads();
    for (int j = beg + t; j < end; j += 256) {
        int c = sbuf_c[j];
        int pos = atomicAdd(&lcur[c], 1);
        lbuf[pos] = sbuf_src[j];
    }
    __syncthreads();
    for (int j = t; j < total; j += 256) csr_src[beg + j] = lbuf[j];
}

// ---------------- fused agg + GEMM: 16 nodes per block ----------------
// Phase A: 4 waves x 4 nodes aggregate (gather h2 rows) -> relu -> fp16 rows in LDS.
// Phase B: same waves run the 16-row MFMA tile against W (NC cols).
// HEAD: fp32 out + gemm bias.
template<int NC, bool HEAD>
__global__ __launch_bounds__(256) void agg_gemm_kernel(
    const __half* __restrict__ h2, const int* __restrict__ row_ptr,
    const int* __restrict__ csr_src, const float* __restrict__ dinv,
    const float* __restrict__ bias,
    const __half* __restrict__ Bh, const __half* __restrict__ Bl,
    const float* __restrict__ gbias, void* __restrict__ Cv, int n) {
    __shared__ __half Als[16][AROW];
    int wave = threadIdx.x >> 6;
    int lane = threadIdx.x & 63;
    int loff = lane << 1;
    int m0 = blockIdx.x << 4;

    // ---- Phase A: aggregate 4 nodes per wave ----
#pragma unroll
    for (int k = 0; k < 4; ++k) {
        int lr = wave * 4 + k;
        int wid = m0 + lr;
        if (wid >= n) break;
        int beg = row_ptr[wid];
        int end = row_ptr[wid + 1];
        float dv = dinv[wid];
        float ax = 0.f, ay = 0.f;
        for (int base = beg; base < end; base += 64) {
            int cnt = end - base;
            if (cnt > 64) cnt = 64;
            int msrc = 0;
            float mw = 0.f;
            if (lane < cnt) {
                msrc = csr_src[base + lane];
                mw = dinv[msrc] * dv;
            }
            int j = 0;
            for (; j + 8 <= cnt; j += 8) {
                int s0 = __shfl(msrc, j),     s1 = __shfl(msrc, j + 1);
                int s2 = __shfl(msrc, j + 2), s3 = __shfl(msrc, j + 3);
                int s4 = __shfl(msrc, j + 4), s5 = __shfl(msrc, j + 5);
                int s6 = __shfl(msrc, j + 6), s7 = __shfl(msrc, j + 7);
                float w0 = __shfl(mw, j),     w1 = __shfl(mw, j + 1);
                float w2 = __shfl(mw, j + 2), w3 = __shfl(mw, j + 3);
                float w4 = __shfl(mw, j + 4), w5 = __shfl(mw, j + 5);
                float w6 = __shfl(mw, j + 6), w7 = __shfl(mw, j + 7);
                float2 v0 = __half22float2(*(const __half2*)(h2 + ((size_t)s0 << 7) + loff));
                float2 v1 = __half22float2(*(const __half2*)(h2 + ((size_t)s1 << 7) + loff));
                float2 v2 = __half22float2(*(const __half2*)(h2 + ((size_t)s2 << 7) + loff));
                float2 v3 = __half22float2(*(const __half2*)(h2 + ((size_t)s3 << 7) + loff));
                float2 v4 = __half22float2(*(const __half2*)(h2 + ((size_t)s4 << 7) + loff));
                float2 v5 = __half22float2(*(const __half2*)(h2 + ((size_t)s5 << 7) + loff));
                float2 v6 = __half22float2(*(const __half2*)(h2 + ((size_t)s6 << 7) + loff));
                float2 v7 = __half22float2(*(const __half2*)(h2 + ((size_t)s7 << 7) + loff));
                ax = fmaf(v0.x, w0, ax); ay = fmaf(v0.y, w0, ay);
                ax = fmaf(v1.x, w1, ax); ay = fmaf(v1.y, w1, ay);
                ax = fmaf(v2.x, w2, ax); ay = fmaf(v2.y, w2, ay);
                ax = fmaf(v3.x, w3, ax); ay = fmaf(v3.y, w3, ay);
                ax = fmaf(v4.x, w4, ax); ay = fmaf(v4.y, w4, ay);
                ax = fmaf(v5.x, w5, ax); ay = fmaf(v5.y, w5, ay);
                ax = fmaf(v6.x, w6, ax); ay = fmaf(v6.y, w6, ay);
                ax = fmaf(v7.x, w7, ax); ay = fmaf(v7.y, w7, ay);
            }
            for (; j + 4 <= cnt; j += 4) {
                int s0 = __shfl(msrc, j),     s1 = __shfl(msrc, j + 1);
                int s2 = __shfl(msrc, j + 2), s3 = __shfl(msrc, j + 3);
                float w0 = __shfl(mw, j),     w1 = __shfl(mw, j + 1);
                float w2 = __shfl(mw, j + 2), w3 = __shfl(mw, j + 3);
                float2 v0 = __half22float2(*(const __half2*)(h2 + ((size_t)s0 << 7) + loff));
                float2 v1 = __half22float2(*(const __half2*)(h2 + ((size_t)s1 << 7) + loff));
                float2 v2 = __half22float2(*(const __half2*)(h2 + ((size_t)s2 << 7) + loff));
                float2 v3 = __half22float2(*(const __half2*)(h2 + ((size_t)s3 << 7) + loff));
                ax = fmaf(v0.x, w0, ax); ay = fmaf(v0.y, w0, ay);
                ax = fmaf(v1.x, w1, ax); ay = fmaf(v1.y, w1, ay);
                ax = fmaf(v2.x, w2, ax); ay = fmaf(v2.y, w2, ay);
                ax = fmaf(v3.x, w3, ax); ay = fmaf(v3.y, w3, ay);
            }
            for (; j < cnt; ++j) {
                int s = __shfl(msrc, j);
                float w = __shfl(mw, j);
                float2 v = __half22float2(*(const __half2*)(h2 + ((size_t)s << 7) + loff));
                ax = fmaf(v.x, w, ax); ay = fmaf(v.y, w, ay);
            }
        }
        float sn = dv * dv;
        float2 self = __half22float2(*(const __half2*)(h2 + ((size_t)wid << 7) + loff));
        float2 b = *(const float2*)(bias + loff);
        float ox = fmaxf(fmaf(self.x, sn, ax) + b.x, 0.f);
        float oy = fmaxf(fmaf(self.y, sn, ay) + b.y, 0.f);
        *(__half2*)&Als[lr][loff] = __float22half2_rn(make_float2(ox, oy));
    }
    __syncthreads();

    // ---- Phase B: 16-row GEMM tile, NT column tiles split across 4 waves ----
    constexpr int NT = NC / 16;         // 8 (hidden) or 4 (head)
    constexpr int TPW = NT / 4;         // tiles per wave: 2 or 1
    int mr = lane & 15;
    int kq = (lane >> 4) << 3;
    const __half* bh = Bh + (size_t)mr * 128 + kq;
    const __half* bl = Bl + (size_t)mr * 128 + kq;

    f32x4 acc[TPW];
#pragma unroll
    for (int t = 0; t < TPW; ++t) acc[t] = (f32x4){0.f, 0.f, 0.f, 0.f};
#pragma unroll
    for (int kc = 0; kc < 128; kc += 32) {
        f16x8 a = *(const f16x8*)&Als[mr][kq + kc];
#pragma unroll
        for (int t = 0; t < TPW; ++t) {
            int tile = wave * TPW + t;
            f16x8 wh = *(const f16x8*)(bh + (size_t)tile * 16 * 128 + kc);
            f16x8 wl = *(const f16x8*)(bl + (size_t)tile * 16 * 128 + kc);
            acc[t] = __builtin_amdgcn_mfma_f32_16x16x32_f16(a, wh, acc[t], 0, 0, 0);
            acc[t] = __builtin_amdgcn_mfma_f32_16x16x32_f16(a, wl, acc[t], 0, 0, 0);
        }
    }
    int r0 = m0 + ((lane >> 4) << 2);
    int cc = lane & 15;
#pragma unroll
    for (int t = 0; t < TPW; ++t) {
        int tile = wave * TPW + t;
        float bsv = HEAD ? gbias[tile * 16 + cc] : 0.f;
#pragma unroll
        for (int r = 0; r < 4; ++r) {
            if (r0 + r >= n) break;
            size_t idx = (size_t)(r0 + r) * NC + tile * 16 + cc;
            float val = acc[t][r] + bsv;
            if (HEAD)
                ((float*)Cv)[idx] = val;
            else
                ((__half*)Cv)[idx] = __float2half_rn(val);
        }
    }
}

extern "C" void kernel_launch(void* const* d_in, const int* in_sizes, int n_in,
                              void* d_out, int out_size, void* d_ws, size_t ws_size,
                              hipStream_t stream) {
    const float* x  = (const float*)d_in[0];
    const int* ei   = (const int*)d_in[1];
    const float* W0 = (const float*)d_in[2];
    const float* b0 = (const float*)d_in[3];
    const float* W1 = (const float*)d_in[4];
    const float* b1 = (const float*)d_in[5];
    const float* W2 = (const float*)d_in[6];
    const float* b2 = (const float*)d_in[7];
    const float* Wl = (const float*)d_in[8];
    const float* bl = (const float*)d_in[9];
    float* out = (float*)d_out;

    const int N = N_NODES;
    const int E = in_sizes[1] / 2;
    const int* row = ei;
    const int* col = ei + E;
    const int chunk = (((E + NBLK - 1) / NBLK) + 3) & ~3;  // 4-aligned chunks

    char* ws = (char*)d_ws;
    auto alloc = [&](size_t bytes) {
        char* p = ws;
        ws += (bytes + 255) & ~(size_t)255;
        return p;
    };
    int*   hist    = (int*)alloc((size_t)NBINS * NBLK * 4);
    int*   binBase = (int*)alloc((size_t)(NBINS + 1) * 4);
    int*   sbuf_src= (int*)alloc((size_t)E * 4);
    unsigned char* sbuf_c = (unsigned char*)alloc((size_t)E);
    int*   row_ptr = (int*)alloc((size_t)(N + 1) * 4);
    float* dinv    = (float*)alloc((size_t)N * 4);
    int*   csr_src = (int*)alloc((size_t)E * 4);
    __half* h2a    = (__half*)alloc((size_t)N * HID * 2);
    __half* h2b    = (__half*)alloc((size_t)N * HID * 2);
    __half* Wt_h[4];
    __half* Wt_l[4];
    for (int i = 0; i < 3; ++i) {
        Wt_h[i] = (__half*)alloc((size_t)HID * HID * 2);
        Wt_l[i] = (__half*)alloc((size_t)HID * HID * 2);
    }
    Wt_h[3] = (__half*)alloc((size_t)CLS * HID * 2);
    Wt_l[3] = (__half*)alloc((size_t)CLS * HID * 2);

    // K1: histogram + weight split
    hist_wsplit_kernel<<<NBLK, 256, 0, stream>>>(col, hist, W0, W1, W2, Wl,
        Wt_h[0], Wt_l[0], Wt_h[1], Wt_l[1], Wt_h[2], Wt_l[2], Wt_h[3], Wt_l[3], E, chunk);
    // K2: bin-sorted scatter (self-computed cursors)
    scatter_kernel<<<NBLK, 256, 0, stream>>>(row, col, hist, binBase, sbuf_src, sbuf_c, E, chunk);
    // K3: CSR placement fused with GEMM-0 (independent workloads)
    csrplace_gemm0_kernel<<<NBINS + GEMM0_BLOCKS, 256, 0, stream>>>(
        binBase, sbuf_src, sbuf_c, dinv, row_ptr, csr_src,
        x, Wt_h[0], Wt_l[0], h2a, N, E);

    const int fusedBlocks = (N + 15) / 16;  // 3125

    // K4: agg(layer0) + GEMM@W1
    agg_gemm_kernel<128, false><<<fusedBlocks, 256, 0, stream>>>(
        h2a, row_ptr, csr_src, dinv, b0, Wt_h[1], Wt_l[1], nullptr, h2b, N);
    // K5: agg(layer1) + GEMM@W2
    agg_gemm_kernel<128, false><<<fusedBlocks, 256, 0, stream>>>(
        h2b, row_ptr, csr_src, dinv, b1, Wt_h[2], Wt_l[2], nullptr, h2a, N);
    // K6: agg(layer2) + head GEMM@Wl (+bl, fp32 out)
    agg_gemm_kernel<64, true><<<fusedBlocks, 256, 0, stream>>>(
        h2a, row_ptr, csr_src, dinv, b2, Wt_h[3], Wt_l[3], bl, out, N);
}